// Round 1
// baseline (1235.048 us; speedup 1.0000x reference)
//
#include <hip/hip_runtime.h>

#define D 64

// ---------------------------------------------------------------- degree count
__global__ void deg_kernel(const int* __restrict__ src, const int* __restrict__ dst,
                           float* __restrict__ deg_out, float* __restrict__ deg_in, int E) {
    int e = blockIdx.x * blockDim.x + threadIdx.x;
    if (e < E) {
        atomicAdd(&deg_out[src[e]], 1.0f);
        atomicAdd(&deg_in[dst[e]], 1.0f);
    }
}

// ---------------------------------------------------------------- edge norms
__global__ void norm_kernel(const int* __restrict__ src, const int* __restrict__ dst,
                            const float* __restrict__ deg_out, const float* __restrict__ deg_in,
                            float* __restrict__ normv, int E) {
    int e = blockIdx.x * blockDim.x + threadIdx.x;
    if (e < E) {
        float a = fmaxf(deg_out[src[e]], 1.0f);
        float b = fmaxf(deg_in[dst[e]], 1.0f);
        normv[e] = 1.0f / sqrtf(a * b);
    }
}

// ---------------------------------------------------------------- weighted scatter: S[dst] += norm * X[src]
// one wave (64 lanes) per edge; lane = feature index
__global__ __launch_bounds__(256) void scatter_kernel(
    const int* __restrict__ src, const int* __restrict__ dst,
    const float* __restrict__ normv, const float* __restrict__ X,
    float* __restrict__ S, int E) {
    int tid = blockIdx.x * blockDim.x + threadIdx.x;
    int lane = threadIdx.x & 63;
    int e = tid >> 6;
    if (e < E) {
        int ew = __builtin_amdgcn_readfirstlane(e);   // wave-uniform -> scalar loads
        int sj = src[ew];
        int di = dst[ew];
        float nv = normv[ew];
        float val = nv * X[sj * D + lane];
        atomicAdd(&S[di * D + lane], val);
    }
}

// ---------------------------------------------------------------- combine: Out = (X+S)@W1 + (X*S)@W2, optional relu
// wave per row; lane owns output column; W1/W2 staged in LDS
__global__ __launch_bounds__(256) void combine_kernel(
    const float* __restrict__ Xin, const float* __restrict__ S,
    const float* __restrict__ W1, const float* __restrict__ W2,
    float* __restrict__ Out, int n, int relu_flag) {
    __shared__ float w1[D * D];
    __shared__ float w2[D * D];
    for (int i = threadIdx.x; i < D * D; i += blockDim.x) {
        w1[i] = W1[i];
        w2[i] = W2[i];
    }
    __syncthreads();
    int lane = threadIdx.x & 63;
    int wid = threadIdx.x >> 6;
    int wavesPerBlock = blockDim.x >> 6;
    int waveId = blockIdx.x * wavesPerBlock + wid;
    int nWaves = gridDim.x * wavesPerBlock;
    for (int row = waveId; row < n; row += nWaves) {
        float x = Xin[row * D + lane];
        float s = S[row * D + lane];
        float u = x + s;
        float v = x * s;
        float acc = 0.0f;
#pragma unroll
        for (int k = 0; k < D; ++k) {
            float uk = __shfl(u, k, 64);   // readlane broadcast (k is literal after unroll)
            float vk = __shfl(v, k, 64);
            acc = fmaf(uk, w1[k * D + lane], acc);
            acc = fmaf(vk, w2[k * D + lane], acc);
        }
        if (relu_flag) acc = fmaxf(acc, 0.0f);
        Out[row * D + lane] = acc;
    }
}

extern "C" void kernel_launch(void* const* d_in, const int* in_sizes, int n_in,
                              void* d_out, int out_size, void* d_ws, size_t ws_size,
                              hipStream_t stream) {
    const float* x    = (const float*)d_in[0];
    const int*   src  = (const int*)d_in[1];
    const int*   dst  = (const int*)d_in[2];
    const float* W1_1 = (const float*)d_in[3];
    const float* W2_1 = (const float*)d_in[4];
    const float* W1_2 = (const float*)d_in[5];
    const float* W2_2 = (const float*)d_in[6];
    float* out = (float*)d_out;

    const int N = in_sizes[0] / D;
    const int E = in_sizes[1];

    float* ws       = (float*)d_ws;
    float* deg_out  = ws;                         // N
    float* deg_in   = ws + N;                     // N
    float* normv    = ws + 2 * (size_t)N;         // E
    float* S        = ws + 2 * (size_t)N + E;     // N*D

    const int tb = 256;
    const int ne_blocks = (E + tb - 1) / tb;
    const long tot = (long)E * D;
    const int ns_blocks = (int)((tot + tb - 1) / tb);

    // degrees + norms (shared by both layers)
    hipMemsetAsync(deg_out, 0, sizeof(float) * 2 * (size_t)N, stream);
    deg_kernel<<<ne_blocks, tb, 0, stream>>>(src, dst, deg_out, deg_in, E);
    norm_kernel<<<ne_blocks, tb, 0, stream>>>(src, dst, deg_out, deg_in, normv, E);

    // ---- layer 1: h = relu((x+S)@W1_1 + (x*S)@W2_1), h lives in d_out
    hipMemsetAsync(S, 0, sizeof(float) * (size_t)N * D, stream);
    scatter_kernel<<<ns_blocks, tb, 0, stream>>>(src, dst, normv, x, S, E);
    combine_kernel<<<1024, tb, 0, stream>>>(x, S, W1_1, W2_1, out, N, 1);

    // ---- layer 2: out = (h+S)@W1_2 + (h*S)@W2_2
    hipMemsetAsync(S, 0, sizeof(float) * (size_t)N * D, stream);
    scatter_kernel<<<ns_blocks, tb, 0, stream>>>(src, dst, normv, out, S, E);
    combine_kernel<<<1024, tb, 0, stream>>>(out, S, W1_2, W2_2, out, N, 0);
}

// Round 2
// 804.869 us; speedup vs baseline: 1.5345x; 1.5345x over previous
//
#include <hip/hip_runtime.h>

#define D 64
#define SCAN_CHUNK 1024
#define MAX_CHUNKS 128

__device__ int g_partials[MAX_CHUNKS];

// ------------------------------------------------ histogram (degrees)
__global__ __launch_bounds__(256) void hist_kernel(
    const int* __restrict__ src, const int* __restrict__ dst,
    int* __restrict__ cnt_src, int* __restrict__ cnt_dst, int E) {
    int e = blockIdx.x * blockDim.x + threadIdx.x;
    if (e < E) {
        atomicAdd(&cnt_src[src[e]], 1);
        atomicAdd(&cnt_dst[dst[e]], 1);
    }
}

// ------------------------------------------------ exclusive scan (3 kernels)
__global__ __launch_bounds__(256) void scanA(const int* __restrict__ cnt, int n) {
    __shared__ int red[256];
    int b = blockIdx.x, t = threadIdx.x;
    int base = b * SCAN_CHUNK + t * 4;
    int s = 0;
#pragma unroll
    for (int j = 0; j < 4; ++j) {
        int i = base + j;
        if (i < n) s += cnt[i];
    }
    red[t] = s;
    __syncthreads();
    for (int off = 128; off > 0; off >>= 1) {
        if (t < off) red[t] += red[t + off];
        __syncthreads();
    }
    if (t == 0) g_partials[b] = red[0];
}

__global__ __launch_bounds__(128) void scanB(int nchunks) {
    __shared__ int sh[MAX_CHUNKS];
    int t = threadIdx.x;
    int v = (t < nchunks) ? g_partials[t] : 0;
    sh[t] = v;
    __syncthreads();
    for (int off = 1; off < MAX_CHUNKS; off <<= 1) {
        int a = (t >= off) ? sh[t - off] : 0;
        __syncthreads();
        sh[t] += a;
        __syncthreads();
    }
    if (t < nchunks) g_partials[t] = sh[t] - v;  // exclusive
}

__global__ __launch_bounds__(256) void scanC(int* __restrict__ cnt, int n) {
    __shared__ int sums[256];
    int b = blockIdx.x, t = threadIdx.x;
    int base = b * SCAN_CHUNK + t * 4;
    int v[4];
    int tot = 0;
#pragma unroll
    for (int j = 0; j < 4; ++j) {
        int i = base + j;
        v[j] = (i < n) ? cnt[i] : 0;
        tot += v[j];
    }
    sums[t] = tot;
    __syncthreads();
    for (int off = 1; off < 256; off <<= 1) {
        int a = (t >= off) ? sums[t - off] : 0;
        __syncthreads();
        sums[t] += a;
        __syncthreads();
    }
    int run = sums[t] - tot + g_partials[b];  // exclusive base for this thread
#pragma unroll
    for (int j = 0; j < 4; ++j) {
        int i = base + j;
        if (i < n) cnt[i] = run;
        run += v[j];
    }
}

// ------------------------------------------------ reorder: CSR-by-dst build
// offs[] holds START offsets; atomic cursor mutates them into END offsets.
__global__ __launch_bounds__(256) void reorder_kernel(
    const int* __restrict__ src, const int* __restrict__ dst,
    int* __restrict__ offs, int* __restrict__ sortedSrc, int E) {
    int e = blockIdx.x * blockDim.x + threadIdx.x;
    if (e < E) {
        int p = atomicAdd(&offs[dst[e]], 1);
        sortedSrc[p] = src[e];
    }
}

// ------------------------------------------------ gather: S[i] = sum norm * X[src]
// wave per node, lane = feature. After reorder: range_i = [i? offs[i-1]:0, offs[i])
__global__ __launch_bounds__(256) void gather_kernel(
    const int* __restrict__ offs, const int* __restrict__ sortedSrc,
    const int* __restrict__ cnt_src, const float* __restrict__ X,
    float* __restrict__ S, int n) {
    int lane = threadIdx.x & 63;
    int node = blockIdx.x * 4 + (threadIdx.x >> 6);
    if (node >= n) return;
    int start = node ? offs[node - 1] : 0;
    int end = offs[node];
    float din = (float)(end - start);  // deg_in >= 1 whenever the loop runs
    float acc = 0.0f;
    for (int p = start; p < end; ++p) {
        int sj = sortedSrc[p];                    // wave-uniform -> scalar load
        float dout = (float)cnt_src[sj];          // wave-uniform -> scalar load
        float nrm = rsqrtf(dout * din);
        acc = fmaf(nrm, X[(size_t)sj * D + lane], acc);
    }
    S[(size_t)node * D + lane] = acc;
}

// ------------------------------------------------ combine: Out = (X+S)@W1 + (X*S)@W2
// lane owns a ROW: u_k/v_k are lane-local; W[k*64+c] is wave-uniform -> s_load.
__global__ __launch_bounds__(256) void combine_kernel(
    const float* X, const float* S,
    const float* __restrict__ W1, const float* __restrict__ W2,
    float* Out, int n, int relu_flag) {
    int row = blockIdx.x * blockDim.x + threadIdx.x;
    if (row >= n) return;
    const float4* x4 = (const float4*)(X + (size_t)row * D);
    const float4* s4 = (const float4*)(S + (size_t)row * D);
    float acc[D];
#pragma unroll
    for (int c = 0; c < D; ++c) acc[c] = 0.0f;

    float4 xc = x4[0], sc = s4[0];
    for (int kk = 0; kk < 16; ++kk) {
        float4 xn, sn;
        if (kk < 15) { xn = x4[kk + 1]; sn = s4[kk + 1]; }
#pragma unroll
        for (int j = 0; j < 4; ++j) {
            int k = (kk << 2) + j;
            float xk = ((const float*)&xc)[j];
            float sk = ((const float*)&sc)[j];
            float u = xk + sk;
            float v = xk * sk;
#pragma unroll
            for (int c = 0; c < D; ++c) {
                acc[c] = fmaf(u, W1[k * D + c], acc[c]);  // W1[..] uniform -> SGPR
                acc[c] = fmaf(v, W2[k * D + c], acc[c]);
            }
        }
        xc = xn; sc = sn;
    }
    float4* o4 = (float4*)(Out + (size_t)row * D);
#pragma unroll
    for (int cc = 0; cc < 16; ++cc) {
        float4 o;
        o.x = acc[cc * 4 + 0];
        o.y = acc[cc * 4 + 1];
        o.z = acc[cc * 4 + 2];
        o.w = acc[cc * 4 + 3];
        if (relu_flag) {
            o.x = fmaxf(o.x, 0.0f); o.y = fmaxf(o.y, 0.0f);
            o.z = fmaxf(o.z, 0.0f); o.w = fmaxf(o.w, 0.0f);
        }
        o4[cc] = o;
    }
}

extern "C" void kernel_launch(void* const* d_in, const int* in_sizes, int n_in,
                              void* d_out, int out_size, void* d_ws, size_t ws_size,
                              hipStream_t stream) {
    const float* x    = (const float*)d_in[0];
    const int*   src  = (const int*)d_in[1];
    const int*   dst  = (const int*)d_in[2];
    const float* W1_1 = (const float*)d_in[3];
    const float* W2_1 = (const float*)d_in[4];
    const float* W1_2 = (const float*)d_in[5];
    const float* W2_2 = (const float*)d_in[6];
    float* out = (float*)d_out;

    const int N = in_sizes[0] / D;
    const int E = in_sizes[1];

    // ws layout (ints/floats, 4B each): offs[N] | cnt_src[N] | sortedSrc[E] | S[N*D]
    int*   offs      = (int*)d_ws;
    int*   cnt_src   = offs + N;
    int*   sortedSrc = offs + 2 * (size_t)N;
    float* S         = (float*)(offs + 2 * (size_t)N + E);

    const int tb = 256;
    const int e_blocks = (E + tb - 1) / tb;
    const int nchunks  = (N + SCAN_CHUNK - 1) / SCAN_CHUNK;   // 98 for N=100000
    const int n_blocks = (N + tb - 1) / tb;
    const int g_blocks = (N + 3) / 4;                          // 4 waves/block

    // ---- CSR-by-dst build (shared by both layers)
    hipMemsetAsync(offs, 0, sizeof(int) * 2 * (size_t)N, stream);
    hist_kernel<<<e_blocks, tb, 0, stream>>>(src, dst, cnt_src, offs, E);
    scanA<<<nchunks, tb, 0, stream>>>(offs, N);
    scanB<<<1, 128, 0, stream>>>(nchunks);
    scanC<<<nchunks, tb, 0, stream>>>(offs, N);
    reorder_kernel<<<e_blocks, tb, 0, stream>>>(src, dst, offs, sortedSrc, E);

    // ---- layer 1: h = relu((x+S)@W1_1 + (x*S)@W2_1), h lives in d_out
    gather_kernel<<<g_blocks, tb, 0, stream>>>(offs, sortedSrc, cnt_src, x, S, N);
    combine_kernel<<<n_blocks, tb, 0, stream>>>(x, S, W1_1, W2_1, out, N, 1);

    // ---- layer 2: out = (h+S)@W1_2 + (h*S)@W2_2
    gather_kernel<<<g_blocks, tb, 0, stream>>>(offs, sortedSrc, cnt_src, out, S, N);
    combine_kernel<<<n_blocks, tb, 0, stream>>>(out, S, W1_2, W2_2, out, N, 0);
}

// Round 3
// 643.598 us; speedup vs baseline: 1.9190x; 1.2506x over previous
//
#include <hip/hip_runtime.h>

#define D 64
#define SCAN_CHUNK 1024
#define MAX_CHUNKS 128

__device__ int g_partials[MAX_CHUNKS];

// ------------------------------------------------ histogram (degrees)
__global__ __launch_bounds__(256) void hist_kernel(
    const int* __restrict__ src, const int* __restrict__ dst,
    int* __restrict__ cnt_src, int* __restrict__ cnt_dst, int E) {
    int e = blockIdx.x * blockDim.x + threadIdx.x;
    if (e < E) {
        atomicAdd(&cnt_src[src[e]], 1);
        atomicAdd(&cnt_dst[dst[e]], 1);
    }
}

// ------------------------------------------------ rs_src[i] = 1/sqrt(max(deg_out,1))
__global__ __launch_bounds__(256) void rs_kernel(
    const int* __restrict__ cnt_src, float* __restrict__ rs, int n) {
    int i = blockIdx.x * blockDim.x + threadIdx.x;
    if (i < n) rs[i] = rsqrtf((float)max(cnt_src[i], 1));
}

// ------------------------------------------------ exclusive scan (3 kernels)
__global__ __launch_bounds__(256) void scanA(const int* __restrict__ cnt, int n) {
    __shared__ int red[256];
    int b = blockIdx.x, t = threadIdx.x;
    int base = b * SCAN_CHUNK + t * 4;
    int s = 0;
#pragma unroll
    for (int j = 0; j < 4; ++j) {
        int i = base + j;
        if (i < n) s += cnt[i];
    }
    red[t] = s;
    __syncthreads();
    for (int off = 128; off > 0; off >>= 1) {
        if (t < off) red[t] += red[t + off];
        __syncthreads();
    }
    if (t == 0) g_partials[b] = red[0];
}

__global__ __launch_bounds__(128) void scanB(int nchunks) {
    __shared__ int sh[MAX_CHUNKS];
    int t = threadIdx.x;
    int v = (t < nchunks) ? g_partials[t] : 0;
    sh[t] = v;
    __syncthreads();
    for (int off = 1; off < MAX_CHUNKS; off <<= 1) {
        int a = (t >= off) ? sh[t - off] : 0;
        __syncthreads();
        sh[t] += a;
        __syncthreads();
    }
    if (t < nchunks) g_partials[t] = sh[t] - v;  // exclusive
}

// out-of-place: offs[i] = exclusive_prefix(cnt)[i]  (cnt preserved)
__global__ __launch_bounds__(256) void scanC(const int* __restrict__ cnt,
                                             int* __restrict__ offs, int n) {
    __shared__ int sums[256];
    int b = blockIdx.x, t = threadIdx.x;
    int base = b * SCAN_CHUNK + t * 4;
    int v[4];
    int tot = 0;
#pragma unroll
    for (int j = 0; j < 4; ++j) {
        int i = base + j;
        v[j] = (i < n) ? cnt[i] : 0;
        tot += v[j];
    }
    sums[t] = tot;
    __syncthreads();
    for (int off = 1; off < 256; off <<= 1) {
        int a = (t >= off) ? sums[t - off] : 0;
        __syncthreads();
        sums[t] += a;
        __syncthreads();
    }
    int run = sums[t] - tot + g_partials[b];
#pragma unroll
    for (int j = 0; j < 4; ++j) {
        int i = base + j;
        if (i < n) offs[i] = run;
        run += v[j];
    }
}

// ------------------------------------------------ reorder: CSR-by-dst build
// offs[] holds START offsets; atomic cursor mutates them into END offsets.
// gather later recovers start = offs[i] - cnt_dst[i].
__global__ __launch_bounds__(256) void reorder_kernel(
    const int* __restrict__ src, const int* __restrict__ dst,
    int* __restrict__ offs, int* __restrict__ sortedSrc, int E) {
    int e = blockIdx.x * blockDim.x + threadIdx.x;
    if (e < E) {
        int p = atomicAdd(&offs[dst[e]], 1);
        sortedSrc[p] = src[e];
    }
}

// ------------------------------------------------ gather: S[i] = rs_dst[i] * sum rs_src[sj] * X[sj]
// wave per node, lane = feature; 4-wide unroll for MLP.
__global__ __launch_bounds__(256) void gather_kernel(
    const int* __restrict__ offs, const int* __restrict__ cnt_dst,
    const int* __restrict__ sortedSrc, const float* __restrict__ rs_src,
    const float* __restrict__ X, float* __restrict__ S, int n) {
    int lane = threadIdx.x & 63;
    int node = blockIdx.x * 4 + (threadIdx.x >> 6);
    if (node >= n) return;
    int end = offs[node];
    int cnt = cnt_dst[node];
    int start = end - cnt;
    float acc = 0.0f;
    int p = start;
    for (; p + 4 <= end; p += 4) {
        int s0 = sortedSrc[p + 0];
        int s1 = sortedSrc[p + 1];
        int s2 = sortedSrc[p + 2];
        int s3 = sortedSrc[p + 3];
        float w0 = rs_src[s0];
        float w1 = rs_src[s1];
        float w2 = rs_src[s2];
        float w3 = rs_src[s3];
        float r0 = X[(size_t)s0 * D + lane];
        float r1 = X[(size_t)s1 * D + lane];
        float r2 = X[(size_t)s2 * D + lane];
        float r3 = X[(size_t)s3 * D + lane];
        acc = fmaf(w0, r0, acc);
        acc = fmaf(w1, r1, acc);
        acc = fmaf(w2, r2, acc);
        acc = fmaf(w3, r3, acc);
    }
    for (; p < end; ++p) {
        int sj = sortedSrc[p];
        acc = fmaf(rs_src[sj], X[(size_t)sj * D + lane], acc);
    }
    float rd = rsqrtf((float)max(cnt, 1));
    S[(size_t)node * D + lane] = acc * rd;
}

// ------------------------------------------------ combine: Out = (X+S)@W1 + (X*S)@W2
// lane owns a ROW: u_k/v_k lane-local; W[k*D+c] wave-uniform -> s_load.
__global__ __launch_bounds__(256) void combine_kernel(
    const float* X, const float* S,
    const float* __restrict__ W1, const float* __restrict__ W2,
    float* Out, int n, int relu_flag) {
    int row = blockIdx.x * blockDim.x + threadIdx.x;
    if (row >= n) return;
    const float4* x4 = (const float4*)(X + (size_t)row * D);
    const float4* s4 = (const float4*)(S + (size_t)row * D);
    float acc[D];
#pragma unroll
    for (int c = 0; c < D; ++c) acc[c] = 0.0f;

    float4 xc = x4[0], sc = s4[0];
    for (int kk = 0; kk < 16; ++kk) {
        float4 xn, sn;
        if (kk < 15) { xn = x4[kk + 1]; sn = s4[kk + 1]; }
#pragma unroll
        for (int j = 0; j < 4; ++j) {
            int k = (kk << 2) + j;
            float xk = ((const float*)&xc)[j];
            float sk = ((const float*)&sc)[j];
            float u = xk + sk;
            float v = xk * sk;
#pragma unroll
            for (int c = 0; c < D; ++c) {
                acc[c] = fmaf(u, W1[k * D + c], acc[c]);
                acc[c] = fmaf(v, W2[k * D + c], acc[c]);
            }
        }
        xc = xn; sc = sn;
    }
    float4* o4 = (float4*)(Out + (size_t)row * D);
#pragma unroll
    for (int cc = 0; cc < 16; ++cc) {
        float4 o;
        o.x = acc[cc * 4 + 0];
        o.y = acc[cc * 4 + 1];
        o.z = acc[cc * 4 + 2];
        o.w = acc[cc * 4 + 3];
        if (relu_flag) {
            o.x = fmaxf(o.x, 0.0f); o.y = fmaxf(o.y, 0.0f);
            o.z = fmaxf(o.z, 0.0f); o.w = fmaxf(o.w, 0.0f);
        }
        o4[cc] = o;
    }
}

extern "C" void kernel_launch(void* const* d_in, const int* in_sizes, int n_in,
                              void* d_out, int out_size, void* d_ws, size_t ws_size,
                              hipStream_t stream) {
    const float* x    = (const float*)d_in[0];
    const int*   src  = (const int*)d_in[1];
    const int*   dst  = (const int*)d_in[2];
    const float* W1_1 = (const float*)d_in[3];
    const float* W2_1 = (const float*)d_in[4];
    const float* W1_2 = (const float*)d_in[5];
    const float* W2_2 = (const float*)d_in[6];
    float* out = (float*)d_out;

    const int N = in_sizes[0] / D;
    const int E = in_sizes[1];

    // ws layout (4B units): cnt_src[N] | cnt_dst[N] | offs[N] | rs_src[N] | sortedSrc[E] | S[N*D]
    int*   cnt_src   = (int*)d_ws;
    int*   cnt_dst   = cnt_src + N;
    int*   offs      = cnt_src + 2 * (size_t)N;
    float* rs_src    = (float*)(cnt_src + 3 * (size_t)N);
    int*   sortedSrc = cnt_src + 4 * (size_t)N;
    float* S         = (float*)(cnt_src + 4 * (size_t)N + E);

    const int tb = 256;
    const int e_blocks = (E + tb - 1) / tb;
    const int nchunks  = (N + SCAN_CHUNK - 1) / SCAN_CHUNK;
    const int n_blocks = (N + tb - 1) / tb;
    const int g_blocks = (N + 3) / 4;

    // ---- CSR-by-dst build (shared by both layers)
    hipMemsetAsync(cnt_src, 0, sizeof(int) * 2 * (size_t)N, stream);
    hist_kernel<<<e_blocks, tb, 0, stream>>>(src, dst, cnt_src, cnt_dst, E);
    rs_kernel<<<n_blocks, tb, 0, stream>>>(cnt_src, rs_src, N);
    scanA<<<nchunks, tb, 0, stream>>>(cnt_dst, N);
    scanB<<<1, 128, 0, stream>>>(nchunks);
    scanC<<<nchunks, tb, 0, stream>>>(cnt_dst, offs, N);
    reorder_kernel<<<e_blocks, tb, 0, stream>>>(src, dst, offs, sortedSrc, E);

    // ---- layer 1: h = relu((x+S)@W1_1 + (x*S)@W2_1), h lives in d_out
    gather_kernel<<<g_blocks, tb, 0, stream>>>(offs, cnt_dst, sortedSrc, rs_src, x, S, N);
    combine_kernel<<<n_blocks, tb, 0, stream>>>(x, S, W1_1, W2_1, out, N, 1);

    // ---- layer 2: out = (h+S)@W1_2 + (h*S)@W2_2
    gather_kernel<<<g_blocks, tb, 0, stream>>>(offs, cnt_dst, sortedSrc, rs_src, out, S, N);
    combine_kernel<<<n_blocks, tb, 0, stream>>>(out, S, W1_2, W2_2, out, N, 0);
}

// Round 4
// 571.992 us; speedup vs baseline: 2.1592x; 1.1252x over previous
//
#include <hip/hip_runtime.h>

#define D 64
#define SCAN_CHUNK 1024
#define MAX_CHUNKS 128
#define BSHIFT 9                 // 512 nodes per bucket
#define BNODES (1 << BSHIFT)
#define CHUNK 8192               // edges per partition block

__device__ int g_partials[MAX_CHUNKS];

// ------------------------------------------------ histogram (degrees)
__global__ __launch_bounds__(256) void hist_kernel(
    const int* __restrict__ src, const int* __restrict__ dst,
    int* __restrict__ cnt_src, int* __restrict__ cnt_dst, int E) {
    int e = blockIdx.x * blockDim.x + threadIdx.x;
    if (e < E) {
        atomicAdd(&cnt_src[src[e]], 1);
        atomicAdd(&cnt_dst[dst[e]], 1);
    }
}

// ------------------------------------------------ rs_src[i] = 1/sqrt(max(deg_out,1))
__global__ __launch_bounds__(256) void rs_kernel(
    const int* __restrict__ cnt_src, float* __restrict__ rs, int n) {
    int i = blockIdx.x * blockDim.x + threadIdx.x;
    if (i < n) rs[i] = rsqrtf((float)max(cnt_src[i], 1));
}

// ------------------------------------------------ exclusive scan (3 kernels)
__global__ __launch_bounds__(256) void scanA(const int* __restrict__ cnt, int n) {
    __shared__ int red[256];
    int b = blockIdx.x, t = threadIdx.x;
    int base = b * SCAN_CHUNK + t * 4;
    int s = 0;
#pragma unroll
    for (int j = 0; j < 4; ++j) {
        int i = base + j;
        if (i < n) s += cnt[i];
    }
    red[t] = s;
    __syncthreads();
    for (int off = 128; off > 0; off >>= 1) {
        if (t < off) red[t] += red[t + off];
        __syncthreads();
    }
    if (t == 0) g_partials[b] = red[0];
}

__global__ __launch_bounds__(128) void scanB(int nchunks) {
    __shared__ int sh[MAX_CHUNKS];
    int t = threadIdx.x;
    int v = (t < nchunks) ? g_partials[t] : 0;
    sh[t] = v;
    __syncthreads();
    for (int off = 1; off < MAX_CHUNKS; off <<= 1) {
        int a = (t >= off) ? sh[t - off] : 0;
        __syncthreads();
        sh[t] += a;
        __syncthreads();
    }
    if (t < nchunks) g_partials[t] = sh[t] - v;  // exclusive
}

// out-of-place: offs[i] = exclusive_prefix(cnt)[i]  (cnt preserved)
__global__ __launch_bounds__(256) void scanC(const int* __restrict__ cnt,
                                             int* __restrict__ offs, int n) {
    __shared__ int sums[256];
    int b = blockIdx.x, t = threadIdx.x;
    int base = b * SCAN_CHUNK + t * 4;
    int v[4];
    int tot = 0;
#pragma unroll
    for (int j = 0; j < 4; ++j) {
        int i = base + j;
        v[j] = (i < n) ? cnt[i] : 0;
        tot += v[j];
    }
    sums[t] = tot;
    __syncthreads();
    for (int off = 1; off < 256; off <<= 1) {
        int a = (t >= off) ? sums[t - off] : 0;
        __syncthreads();
        sums[t] += a;
        __syncthreads();
    }
    int run = sums[t] - tot + g_partials[b];
#pragma unroll
    for (int j = 0; j < 4; ++j) {
        int i = base + j;
        if (i < n) offs[i] = run;
        run += v[j];
    }
}

// ------------------------------------------------ partition pass A: per-(block,bucket) counts
__global__ __launch_bounds__(256) void partA(const int* __restrict__ dst,
                                             int* __restrict__ histA, int E, int G, int NB) {
    __shared__ int h[256];
    int g = blockIdx.x;
    h[threadIdx.x] = 0;
    __syncthreads();
    int base = g * CHUNK;
    int lim = min(E - base, CHUNK);
    for (int i = threadIdx.x; i < lim; i += 256)
        atomicAdd(&h[dst[base + i] >> BSHIFT], 1);
    __syncthreads();
    if (threadIdx.x < NB) histA[threadIdx.x * G + g] = h[threadIdx.x];
}

// ------------------------------------------------ partition pass C: bucket-major reorder (coalesced-ish writes)
__global__ __launch_bounds__(256) void partC(const int* __restrict__ src,
                                             const int* __restrict__ dst,
                                             const int* __restrict__ histAs,
                                             int2* __restrict__ ebuf, int E, int G, int NB) {
    __shared__ int cur[256];
    int g = blockIdx.x;
    if (threadIdx.x < NB) cur[threadIdx.x] = histAs[threadIdx.x * G + g];
    __syncthreads();
    int base = g * CHUNK;
    int lim = min(E - base, CHUNK);
    for (int i = threadIdx.x; i < lim; i += 256) {
        int d = dst[base + i];
        int s = src[base + i];
        int pos = atomicAdd(&cur[d >> BSHIFT], 1);
        ebuf[pos] = make_int2(s, d);
    }
}

// ------------------------------------------------ partition pass D: per-bucket local scatter (LDS cursors, L2-resident window)
__global__ __launch_bounds__(256) void partD(const int2* __restrict__ ebuf,
                                             const int* __restrict__ histAs,
                                             const int* __restrict__ offs,
                                             int* __restrict__ sortedSrc,
                                             int E, int G, int NB, int N) {
    __shared__ int cur[BNODES];
    int b = blockIdx.x;
    int nbase = b << BSHIFT;
    for (int i = threadIdx.x; i < BNODES; i += 256) {
        int node = nbase + i;
        cur[i] = (node < N) ? offs[node] : 0;
    }
    __syncthreads();
    int estart = histAs[b * G];
    int eend = (b + 1 < NB) ? histAs[(b + 1) * G] : E;
    for (int p = estart + threadIdx.x; p < eend; p += 256) {
        int2 e = ebuf[p];
        int pos = atomicAdd(&cur[e.y - nbase], 1);
        sortedSrc[pos] = e.x;
    }
}

// ------------------------------------------------ gather: S[i] = rs_dst[i] * sum rs_src[sj] * X[sj]
// wave per node, lane = feature; 8-wide unroll + clamped predicated tail.
__global__ __launch_bounds__(256) void gather_kernel(
    const int* __restrict__ offs, const int* __restrict__ cnt_dst,
    const int* __restrict__ sortedSrc, const float* __restrict__ rs_src,
    const float* __restrict__ X, float* __restrict__ S, int n) {
    int lane = threadIdx.x & 63;
    int node = blockIdx.x * 4 + (threadIdx.x >> 6);
    if (node >= n) return;
    int start = offs[node];
    int cnt = cnt_dst[node];
    int end = start + cnt;
    float acc = 0.0f;
    int p = start;
    for (; p + 8 <= end; p += 8) {
        int idx[8];
        float w[8];
        float r[8];
#pragma unroll
        for (int j = 0; j < 8; ++j) idx[j] = sortedSrc[p + j];
#pragma unroll
        for (int j = 0; j < 8; ++j) w[j] = rs_src[idx[j]];
#pragma unroll
        for (int j = 0; j < 8; ++j) r[j] = X[(size_t)idx[j] * D + lane];
#pragma unroll
        for (int j = 0; j < 8; ++j) acc = fmaf(w[j], r[j], acc);
    }
    if (p < end) {  // one clamped iteration: loads stay independent, inactive slots re-hit row end-1
        int idx[8];
        float w[8];
        float r[8];
#pragma unroll
        for (int j = 0; j < 8; ++j) {
            int q = p + j;
            int qc = (q < end) ? q : (end - 1);
            idx[j] = sortedSrc[qc];
        }
#pragma unroll
        for (int j = 0; j < 8; ++j) w[j] = (p + j < end) ? rs_src[idx[j]] : 0.0f;
#pragma unroll
        for (int j = 0; j < 8; ++j) r[j] = X[(size_t)idx[j] * D + lane];
#pragma unroll
        for (int j = 0; j < 8; ++j) acc = fmaf(w[j], r[j], acc);
    }
    float rd = rsqrtf((float)max(cnt, 1));
    S[(size_t)node * D + lane] = acc * rd;
}

// ------------------------------------------------ combine: Out = (X+S)@W1 + (X*S)@W2
// lane owns a ROW: u_k/v_k lane-local; W[k*D+c] wave-uniform -> s_load.
__global__ __launch_bounds__(256) void combine_kernel(
    const float* X, const float* S,
    const float* __restrict__ W1, const float* __restrict__ W2,
    float* Out, int n, int relu_flag) {
    int row = blockIdx.x * blockDim.x + threadIdx.x;
    if (row >= n) return;
    const float4* x4 = (const float4*)(X + (size_t)row * D);
    const float4* s4 = (const float4*)(S + (size_t)row * D);
    float acc[D];
#pragma unroll
    for (int c = 0; c < D; ++c) acc[c] = 0.0f;

    float4 xc = x4[0], sc = s4[0];
    for (int kk = 0; kk < 16; ++kk) {
        float4 xn, sn;
        if (kk < 15) { xn = x4[kk + 1]; sn = s4[kk + 1]; }
#pragma unroll
        for (int j = 0; j < 4; ++j) {
            int k = (kk << 2) + j;
            float xk = ((const float*)&xc)[j];
            float sk = ((const float*)&sc)[j];
            float u = xk + sk;
            float v = xk * sk;
#pragma unroll
            for (int c = 0; c < D; ++c) {
                acc[c] = fmaf(u, W1[k * D + c], acc[c]);
                acc[c] = fmaf(v, W2[k * D + c], acc[c]);
            }
        }
        xc = xn; sc = sn;
    }
    float4* o4 = (float4*)(Out + (size_t)row * D);
#pragma unroll
    for (int cc = 0; cc < 16; ++cc) {
        float4 o;
        o.x = acc[cc * 4 + 0];
        o.y = acc[cc * 4 + 1];
        o.z = acc[cc * 4 + 2];
        o.w = acc[cc * 4 + 3];
        if (relu_flag) {
            o.x = fmaxf(o.x, 0.0f); o.y = fmaxf(o.y, 0.0f);
            o.z = fmaxf(o.z, 0.0f); o.w = fmaxf(o.w, 0.0f);
        }
        o4[cc] = o;
    }
}

extern "C" void kernel_launch(void* const* d_in, const int* in_sizes, int n_in,
                              void* d_out, int out_size, void* d_ws, size_t ws_size,
                              hipStream_t stream) {
    const float* x    = (const float*)d_in[0];
    const int*   src  = (const int*)d_in[1];
    const int*   dst  = (const int*)d_in[2];
    const float* W1_1 = (const float*)d_in[3];
    const float* W2_1 = (const float*)d_in[4];
    const float* W1_2 = (const float*)d_in[5];
    const float* W2_2 = (const float*)d_in[6];
    float* out = (float*)d_out;

    const int N = in_sizes[0] / D;
    const int E = in_sizes[1];

    const int NB = (N + BNODES - 1) >> BSHIFT;     // buckets (<=256 for N<=131072)
    const int G  = (E + CHUNK - 1) / CHUNK;        // partition blocks
    const int HL = NB * G;                         // hist matrix length

    // ws layout (4B units):
    // cnt_src[N] | cnt_dst[N] | offs[N] | rs_src[N] | sortedSrc[E] | histA[HL] | histAs[HL] | S[N*D]
    int*   cnt_src   = (int*)d_ws;
    int*   cnt_dst   = cnt_src + N;
    int*   offs      = cnt_src + 2 * (size_t)N;
    float* rs_src    = (float*)(cnt_src + 3 * (size_t)N);
    int*   sortedSrc = cnt_src + 4 * (size_t)N;
    int*   histA     = sortedSrc + E;
    int*   histAs    = histA + HL;
    float* S         = (float*)(histAs + HL);
    int2*  ebuf      = (int2*)S;                   // aliases S (consumed before gather writes S)

    const int tb = 256;
    const int e_blocks = (E + tb - 1) / tb;
    const int n_blocks = (N + tb - 1) / tb;
    const int g_blocks = (N + 3) / 4;
    const int nchunksN = (N + SCAN_CHUNK - 1) / SCAN_CHUNK;
    const int nchunksH = (HL + SCAN_CHUNK - 1) / SCAN_CHUNK;

    // ---- degrees + norms
    hipMemsetAsync(cnt_src, 0, sizeof(int) * 2 * (size_t)N, stream);
    hist_kernel<<<e_blocks, tb, 0, stream>>>(src, dst, cnt_src, cnt_dst, E);
    rs_kernel<<<n_blocks, tb, 0, stream>>>(cnt_src, rs_src, N);

    // ---- offs = exclusive scan of cnt_dst (stays immutable)
    scanA<<<nchunksN, tb, 0, stream>>>(cnt_dst, N);
    scanB<<<1, 128, 0, stream>>>(nchunksN);
    scanC<<<nchunksN, tb, 0, stream>>>(cnt_dst, offs, N);

    // ---- radix-partition CSR build
    partA<<<G, tb, 0, stream>>>(dst, histA, E, G, NB);
    scanA<<<nchunksH, tb, 0, stream>>>(histA, HL);
    scanB<<<1, 128, 0, stream>>>(nchunksH);
    scanC<<<nchunksH, tb, 0, stream>>>(histA, histAs, HL);
    partC<<<G, tb, 0, stream>>>(src, dst, histAs, ebuf, E, G, NB);
    partD<<<NB, tb, 0, stream>>>(ebuf, histAs, offs, sortedSrc, E, G, NB, N);

    // ---- layer 1: h = relu((x+S)@W1_1 + (x*S)@W2_1), h lives in d_out
    gather_kernel<<<g_blocks, tb, 0, stream>>>(offs, cnt_dst, sortedSrc, rs_src, x, S, N);
    combine_kernel<<<n_blocks, tb, 0, stream>>>(x, S, W1_1, W2_1, out, N, 1);

    // ---- layer 2: out = (h+S)@W1_2 + (h*S)@W2_2
    gather_kernel<<<g_blocks, tb, 0, stream>>>(offs, cnt_dst, sortedSrc, rs_src, out, S, N);
    combine_kernel<<<n_blocks, tb, 0, stream>>>(out, S, W1_2, W2_2, out, N, 0);
}

// Round 5
// 475.995 us; speedup vs baseline: 2.5947x; 1.2017x over previous
//
#include <hip/hip_runtime.h>

#define D 64
#define SCAN_CHUNK 1024
#define MAX_CHUNKS 128
#define BSHIFT 9                 // 512 nodes per bucket
#define BNODES (1 << BSHIFT)
#define CHUNK 8192               // edges per partition block

__device__ int g_partials[MAX_CHUNKS];

// ------------------------------------------------ exclusive scan (3 kernels)
__global__ __launch_bounds__(256) void scanA(const int* __restrict__ cnt, int n) {
    __shared__ int red[256];
    int b = blockIdx.x, t = threadIdx.x;
    int base = b * SCAN_CHUNK + t * 4;
    int s = 0;
#pragma unroll
    for (int j = 0; j < 4; ++j) {
        int i = base + j;
        if (i < n) s += cnt[i];
    }
    red[t] = s;
    __syncthreads();
    for (int off = 128; off > 0; off >>= 1) {
        if (t < off) red[t] += red[t + off];
        __syncthreads();
    }
    if (t == 0) g_partials[b] = red[0];
}

__global__ __launch_bounds__(128) void scanB(int nchunks) {
    __shared__ int sh[MAX_CHUNKS];
    int t = threadIdx.x;
    int v = (t < nchunks) ? g_partials[t] : 0;
    sh[t] = v;
    __syncthreads();
    for (int off = 1; off < MAX_CHUNKS; off <<= 1) {
        int a = (t >= off) ? sh[t - off] : 0;
        __syncthreads();
        sh[t] += a;
        __syncthreads();
    }
    if (t < nchunks) g_partials[t] = sh[t] - v;  // exclusive
}

// out-of-place: offs[i] = exclusive_prefix(cnt)[i]  (cnt preserved)
__global__ __launch_bounds__(256) void scanC(const int* __restrict__ cnt,
                                             int* __restrict__ offs, int n) {
    __shared__ int sums[256];
    int b = blockIdx.x, t = threadIdx.x;
    int base = b * SCAN_CHUNK + t * 4;
    int v[4];
    int tot = 0;
#pragma unroll
    for (int j = 0; j < 4; ++j) {
        int i = base + j;
        v[j] = (i < n) ? cnt[i] : 0;
        tot += v[j];
    }
    sums[t] = tot;
    __syncthreads();
    for (int off = 1; off < 256; off <<= 1) {
        int a = (t >= off) ? sums[t - off] : 0;
        __syncthreads();
        sums[t] += a;
        __syncthreads();
    }
    int run = sums[t] - tot + g_partials[b];
#pragma unroll
    for (int j = 0; j < 4; ++j) {
        int i = base + j;
        if (i < n) offs[i] = run;
        run += v[j];
    }
}

// ------------------------------------------------ partAB: per-(chunk,bucket) counts for dst AND src
__global__ __launch_bounds__(256) void partAB(const int* __restrict__ src,
                                              const int* __restrict__ dst,
                                              int* __restrict__ histJ,
                                              int E, int G, int NB, int HL) {
    __shared__ int hD[256], hS[256];
    int g = blockIdx.x;
    hD[threadIdx.x] = 0;
    hS[threadIdx.x] = 0;
    __syncthreads();
    int base = g * CHUNK;
    int lim = min(E - base, CHUNK);
    for (int i = threadIdx.x; i < lim; i += 256) {
        atomicAdd(&hD[dst[base + i] >> BSHIFT], 1);
        atomicAdd(&hS[src[base + i] >> BSHIFT], 1);
    }
    __syncthreads();
    if (threadIdx.x < NB) {
        histJ[threadIdx.x * G + g] = hD[threadIdx.x];
        histJ[HL + threadIdx.x * G + g] = hS[threadIdx.x];
    }
}

// ------------------------------------------------ partCJ: bucket-major reorder for both partitions (SoA)
__global__ __launch_bounds__(256) void partCJ(const int* __restrict__ src,
                                              const int* __restrict__ dst,
                                              const int* __restrict__ histJs,
                                              int* __restrict__ ebufS, int* __restrict__ ebufD,
                                              int* __restrict__ ebufK,
                                              int E, int G, int NB, int HL) {
    __shared__ int curD[256], curK[256];
    int g = blockIdx.x;
    if (threadIdx.x < NB) {
        curD[threadIdx.x] = histJs[threadIdx.x * G + g];
        curK[threadIdx.x] = histJs[HL + threadIdx.x * G + g];
    }
    __syncthreads();
    int base = g * CHUNK;
    int lim = min(E - base, CHUNK);
    for (int i = threadIdx.x; i < lim; i += 256) {
        int d = dst[base + i];
        int s = src[base + i];
        int pD = atomicAdd(&curD[d >> BSHIFT], 1);
        ebufS[pD] = s;
        ebufD[pD] = d;
        int pK = atomicAdd(&curK[s >> BSHIFT], 1) - E;  // src positions offset by E in joint scan
        ebufK[pK] = s;
    }
}

// ------------------------------------------------ partDcount: per-bucket node degrees (LDS), coalesced writes
__global__ __launch_bounds__(256) void partDcount(const int* __restrict__ ebufD,
                                                  const int* __restrict__ ebufK,
                                                  const int* __restrict__ histJs,
                                                  int* __restrict__ cnt_dst, float* __restrict__ rs_src,
                                                  int E, int G, int NB, int HL, int N) {
    __shared__ int cntD[BNODES], cntS[BNODES];
    int b = blockIdx.x;
    int nbase = b << BSHIFT;
    for (int i = threadIdx.x; i < BNODES; i += 256) { cntD[i] = 0; cntS[i] = 0; }
    __syncthreads();
    int dS = histJs[b * G];
    int dE = (b + 1 < NB) ? histJs[(b + 1) * G] : E;
    for (int p = dS + threadIdx.x; p < dE; p += 256)
        atomicAdd(&cntD[ebufD[p] - nbase], 1);
    int kS = histJs[HL + b * G] - E;
    int kE = (b + 1 < NB) ? histJs[HL + (b + 1) * G] - E : E;
    for (int p = kS + threadIdx.x; p < kE; p += 256)
        atomicAdd(&cntS[ebufK[p] - nbase], 1);
    __syncthreads();
    for (int i = threadIdx.x; i < BNODES; i += 256) {
        int node = nbase + i;
        if (node < N) {
            cnt_dst[node] = cntD[i];
            rs_src[node] = rsqrtf((float)max(cntS[i], 1));
        }
    }
}

// ------------------------------------------------ partD2: per-bucket local scatter (LDS cursors)
__global__ __launch_bounds__(256) void partD2(const int* __restrict__ ebufS,
                                              const int* __restrict__ ebufD,
                                              const int* __restrict__ histJs,
                                              const int* __restrict__ offs,
                                              int* __restrict__ sortedSrc,
                                              int E, int G, int NB, int N) {
    __shared__ int cur[BNODES];
    int b = blockIdx.x;
    int nbase = b << BSHIFT;
    for (int i = threadIdx.x; i < BNODES; i += 256) {
        int node = nbase + i;
        cur[i] = (node < N) ? offs[node] : 0;
    }
    __syncthreads();
    int dS = histJs[b * G];
    int dE = (b + 1 < NB) ? histJs[(b + 1) * G] : E;
    for (int p = dS + threadIdx.x; p < dE; p += 256) {
        int d = ebufD[p];
        int s = ebufS[p];
        int pos = atomicAdd(&cur[d - nbase], 1);
        sortedSrc[pos] = s;
    }
}

// ------------------------------------------------ gather: S[i] = rs_dst[i] * sum rs_src[sj] * X[sj]
__global__ __launch_bounds__(256) void gather_kernel(
    const int* __restrict__ offs, const int* __restrict__ cnt_dst,
    const int* __restrict__ sortedSrc, const float* __restrict__ rs_src,
    const float* __restrict__ X, float* __restrict__ S, int n) {
    int lane = threadIdx.x & 63;
    int node = blockIdx.x * 4 + (threadIdx.x >> 6);
    if (node >= n) return;
    int start = offs[node];
    int cnt = cnt_dst[node];
    int end = start + cnt;
    float acc = 0.0f;
    int p = start;
    for (; p + 8 <= end; p += 8) {
        int idx[8];
        float w[8];
        float r[8];
#pragma unroll
        for (int j = 0; j < 8; ++j) idx[j] = sortedSrc[p + j];
#pragma unroll
        for (int j = 0; j < 8; ++j) w[j] = rs_src[idx[j]];
#pragma unroll
        for (int j = 0; j < 8; ++j) r[j] = X[(size_t)idx[j] * D + lane];
#pragma unroll
        for (int j = 0; j < 8; ++j) acc = fmaf(w[j], r[j], acc);
    }
    if (p < end) {  // clamped predicated tail: loads stay independent
        int idx[8];
        float w[8];
        float r[8];
#pragma unroll
        for (int j = 0; j < 8; ++j) {
            int q = p + j;
            int qc = (q < end) ? q : (end - 1);
            idx[j] = sortedSrc[qc];
        }
#pragma unroll
        for (int j = 0; j < 8; ++j) w[j] = (p + j < end) ? rs_src[idx[j]] : 0.0f;
#pragma unroll
        for (int j = 0; j < 8; ++j) r[j] = X[(size_t)idx[j] * D + lane];
#pragma unroll
        for (int j = 0; j < 8; ++j) acc = fmaf(w[j], r[j], acc);
    }
    float rd = rsqrtf((float)max(cnt, 1));
    S[(size_t)node * D + lane] = acc * rd;
}

// ------------------------------------------------ combine: Out = (X+S)@W1 + (X*S)@W2
__global__ __launch_bounds__(256) void combine_kernel(
    const float* X, const float* S,
    const float* __restrict__ W1, const float* __restrict__ W2,
    float* Out, int n, int relu_flag) {
    int row = blockIdx.x * blockDim.x + threadIdx.x;
    if (row >= n) return;
    const float4* x4 = (const float4*)(X + (size_t)row * D);
    const float4* s4 = (const float4*)(S + (size_t)row * D);
    float acc[D];
#pragma unroll
    for (int c = 0; c < D; ++c) acc[c] = 0.0f;

    float4 xc = x4[0], sc = s4[0];
    for (int kk = 0; kk < 16; ++kk) {
        float4 xn, sn;
        if (kk < 15) { xn = x4[kk + 1]; sn = s4[kk + 1]; }
#pragma unroll
        for (int j = 0; j < 4; ++j) {
            int k = (kk << 2) + j;
            float xk = ((const float*)&xc)[j];
            float sk = ((const float*)&sc)[j];
            float u = xk + sk;
            float v = xk * sk;
#pragma unroll
            for (int c = 0; c < D; ++c) {
                acc[c] = fmaf(u, W1[k * D + c], acc[c]);
                acc[c] = fmaf(v, W2[k * D + c], acc[c]);
            }
        }
        xc = xn; sc = sn;
    }
    float4* o4 = (float4*)(Out + (size_t)row * D);
#pragma unroll
    for (int cc = 0; cc < 16; ++cc) {
        float4 o;
        o.x = acc[cc * 4 + 0];
        o.y = acc[cc * 4 + 1];
        o.z = acc[cc * 4 + 2];
        o.w = acc[cc * 4 + 3];
        if (relu_flag) {
            o.x = fmaxf(o.x, 0.0f); o.y = fmaxf(o.y, 0.0f);
            o.z = fmaxf(o.z, 0.0f); o.w = fmaxf(o.w, 0.0f);
        }
        o4[cc] = o;
    }
}

extern "C" void kernel_launch(void* const* d_in, const int* in_sizes, int n_in,
                              void* d_out, int out_size, void* d_ws, size_t ws_size,
                              hipStream_t stream) {
    const float* x    = (const float*)d_in[0];
    const int*   src  = (const int*)d_in[1];
    const int*   dst  = (const int*)d_in[2];
    const float* W1_1 = (const float*)d_in[3];
    const float* W2_1 = (const float*)d_in[4];
    const float* W1_2 = (const float*)d_in[5];
    const float* W2_2 = (const float*)d_in[6];
    float* out = (float*)d_out;

    const int N = in_sizes[0] / D;
    const int E = in_sizes[1];

    const int NB = (N + BNODES - 1) >> BSHIFT;     // node buckets (196 for N=100000)
    const int G  = (E + CHUNK - 1) / CHUNK;        // partition chunks (196)
    const int HL = NB * G;

    // ws layout (4B units):
    // cnt_dst[N] | offs[N] | rs_src[N] | sortedSrc[E] | histJ[2HL] | histJs[2HL] | S[N*D]
    // ebufS/ebufD/ebufK alias S (19.2MB < 25.6MB; all dead before gather writes S).
    int*   cnt_dst   = (int*)d_ws;
    int*   offs      = cnt_dst + N;
    float* rs_src    = (float*)(cnt_dst + 2 * (size_t)N);
    int*   sortedSrc = cnt_dst + 3 * (size_t)N;
    int*   histJ     = sortedSrc + E;
    int*   histJs    = histJ + 2 * (size_t)HL;
    float* S         = (float*)(histJs + 2 * (size_t)HL);
    int*   ebufS     = (int*)S;
    int*   ebufD     = ebufS + E;
    int*   ebufK     = ebufD + E;

    const int tb = 256;
    const int n_blocks = (N + tb - 1) / tb;
    const int g_blocks = (N + 3) / 4;
    const int nchunksN = (N + SCAN_CHUNK - 1) / SCAN_CHUNK;
    const int nchunksJ = (2 * HL + SCAN_CHUNK - 1) / SCAN_CHUNK;

    // ---- joint bucket histograms (dst + src) and joint scan
    partAB<<<G, tb, 0, stream>>>(src, dst, histJ, E, G, NB, HL);
    scanA<<<nchunksJ, tb, 0, stream>>>(histJ, 2 * HL);
    scanB<<<1, 128, 0, stream>>>(nchunksJ);
    scanC<<<nchunksJ, tb, 0, stream>>>(histJ, histJs, 2 * HL);

    // ---- bucket-major reorder for both partitions
    partCJ<<<G, tb, 0, stream>>>(src, dst, histJs, ebufS, ebufD, ebufK, E, G, NB, HL);

    // ---- per-node degrees (coalesced, no global atomics) + rs_src
    partDcount<<<NB, tb, 0, stream>>>(ebufD, ebufK, histJs, cnt_dst, rs_src, E, G, NB, HL, N);

    // ---- offs = exclusive scan of cnt_dst
    scanA<<<nchunksN, tb, 0, stream>>>(cnt_dst, N);
    scanB<<<1, 128, 0, stream>>>(nchunksN);
    scanC<<<nchunksN, tb, 0, stream>>>(cnt_dst, offs, N);

    // ---- CSR scatter
    partD2<<<NB, tb, 0, stream>>>(ebufS, ebufD, histJs, offs, sortedSrc, E, G, NB, N);

    // ---- layer 1: h = relu((x+S)@W1_1 + (x*S)@W2_1), h lives in d_out
    gather_kernel<<<g_blocks, tb, 0, stream>>>(offs, cnt_dst, sortedSrc, rs_src, x, S, N);
    combine_kernel<<<n_blocks, tb, 0, stream>>>(x, S, W1_1, W2_1, out, N, 1);

    // ---- layer 2: out = (h+S)@W1_2 + (h*S)@W2_2
    gather_kernel<<<g_blocks, tb, 0, stream>>>(offs, cnt_dst, sortedSrc, rs_src, out, S, N);
    combine_kernel<<<n_blocks, tb, 0, stream>>>(out, S, W1_2, W2_2, out, N, 0);
}